// Round 12
// baseline (570.718 us; speedup 1.0000x reference)
//
#include <hip/hip_runtime.h>
#include <hip/hip_bf16.h>

#define S_DIM 256
#define I_DIM 64
#define O_DIM 64
#define BATCH 64
#define TT 2048
#define CHUNK 32
#define NCHUNK (TT / CHUNK)     // 64
#define NTASK (BATCH * TT / CHUNK)  // 4096

typedef __attribute__((ext_vector_type(8))) short short8v;      // 8 bf16
typedef _Float16 half8v __attribute__((ext_vector_type(8)));    // 8 fp16
typedef __attribute__((ext_vector_type(4))) float float4v;      // MFMA acc

__device__ inline unsigned short f2bf(float f) {
  unsigned x = __float_as_uint(f);
  unsigned r = (x + 0x7FFFu + ((x >> 16) & 1u)) >> 16;  // RNE
  return (unsigned short)r;
}
__device__ inline short bfr(float x) {
  __hip_bfloat16 h = __float2bfloat16(x);
  return __builtin_bit_cast(short, h);
}

// global -> LDS direct DMA, 16B per lane (dst = wave-uniform base + lane*16)
__device__ inline void gload16(const float* g, float* lds) {
  __builtin_amdgcn_global_load_lds(
      (const __attribute__((address_space(1))) unsigned int*)g,
      (__attribute__((address_space(3))) unsigned int*)lds, 16, 0, 0);
}

// ------------- power-stack doubling: stack[m+j] = stack[j] @ stack[m-1] -------------
__global__ void k_powstage(float* __restrict__ stack, int m) {
  const int j = blockIdx.x >> 8;
  const int i = blockIdx.x & 255;
  const int d = threadIdx.x;
  const float* A = stack + (size_t)j * 65536 + i * 256;
  const float* Bm = stack + (size_t)(m - 1) * 65536;
  float acc = 0.f;
#pragma unroll 8
  for (int k = 0; k < 256; ++k) acc += A[k] * Bm[k * 256 + d];
  stack[(size_t)(m + j) * 65536 + i * 256 + d] = acc;
}

// ------------- f32 -> bf16 elementwise -------------
__global__ void k_bfcvt(const float* __restrict__ src, unsigned short* __restrict__ dst) {
  int i = blockIdx.x * 256 + threadIdx.x;
  float4 v = reinterpret_cast<const float4*>(src)[i];
  ushort4 o;
  o.x = f2bf(v.x); o.y = f2bf(v.y); o.z = f2bf(v.z); o.w = f2bf(v.w);
  reinterpret_cast<ushort4*>(dst)[i] = o;
}

// ------------- f32 matrix -> fp16 hi/lo split -------------
__global__ void k_fsplit16(const float* __restrict__ src, _Float16* __restrict__ hi,
                           _Float16* __restrict__ lo) {
  int idx = blockIdx.x * 256 + threadIdx.x;
  float a = src[idx];
  _Float16 h = (_Float16)a;
  hi[idx] = h;
  lo[idx] = (_Float16)(a - (float)h);
}

// ------------- weight convert: Wd[n][k] = concat(s1,s2) rows, single bf16 -------------
__global__ void k_wcvt(const float* __restrict__ s1, const float* __restrict__ s2,
                       int K1, int K2, unsigned short* __restrict__ hi, int total) {
  int idx = blockIdx.x * 256 + threadIdx.x;
  if (idx >= total) return;
  int KT = K1 + K2;
  int n = idx / KT, k = idx - n * KT;
  float a = (k < K1) ? s1[n * K1 + k] : s2[n * K2 + (k - K1)];
  hi[idx] = f2bf(a);
}

// ---------------- 2-phase LDS-pipelined bf16 MFMA GEMM: out = [A1|A2] @ W^T ----------------
template <int N_TOT, int K1, int K2, int M_TILE, int WIM, int WIN>
__global__ __launch_bounds__(256, 3) void k_tgemm(
    const float* __restrict__ A1, const float* __restrict__ A2,
    const unsigned short* __restrict__ W, float* __restrict__ out) {
  constexpr int KT = K1 + K2;   // 320
  constexpr int NKT = KT / 64;  // 5 K-tiles
  constexpr int MF = M_TILE / WIM / 16;
  constexpr int NF = N_TOT / WIN / 16;
  constexpr int LOGM = (M_TILE == 64) ? 6 : 7;
  constexpr int CPW = M_TILE / 16;  // gload calls per wave per K-tile

  __shared__ float als[2][M_TILE * 64];

  const int tid = threadIdx.x;
  const int wv = tid >> 6, lane = tid & 63;
  const int lo16 = lane & 15, hi4 = lane >> 4;
  const int wm = wv % WIM, wn = wv / WIM;
  const size_t R0 = (size_t)blockIdx.x * M_TILE;
  const int C0 = wn * (N_TOT / WIN);

  auto stage = [&](int buf, int kt) {
#pragma unroll
    for (int c = 0; c < CPW; ++c) {
      const int i = wv * CPW + c;
      const int s = i * 64 + lane;
      const int row = s & (M_TILE - 1);
      const int g = s >> LOGM;
      const int k0 = kt * 64;
      const float* src = (k0 < K1) ? A1 + (R0 + row) * K1 + k0 + g * 4
                                   : A2 + (R0 + row) * K2 + (k0 - K1) + g * 4;
      gload16(src, &als[buf][i * 256]);
    }
  };
  auto aread = [&](int buf, int kkl, int m, int h) -> float4 {
    const int row = wm * (M_TILE / WIM) + m * 16 + lo16;
    const int g = kkl * 8 + hi4 * 2 + h;
    return *reinterpret_cast<const float4*>(&als[buf][(g * M_TILE + row) * 4]);
  };
  auto wload = [&](int kk, int nf) -> short8v {
    return *reinterpret_cast<const short8v*>(
        W + (size_t)(C0 + nf * 16 + lo16) * KT + kk * 32 + hi4 * 8);
  };

  float4v acc[MF][NF];
#pragma unroll
  for (int m = 0; m < MF; ++m)
#pragma unroll
    for (int n = 0; n < NF; ++n) acc[m][n] = (float4v){0.f, 0.f, 0.f, 0.f};

  short8v wr[2][NF];
  stage(0, 0);
#pragma unroll
  for (int nf = 0; nf < NF; ++nf) wr[0][nf] = wload(0, nf);
  __syncthreads();

#pragma unroll
  for (int kt = 0; kt < NKT; ++kt) {
    if (kt + 1 < NKT) stage((kt + 1) & 1, kt + 1);  // DMA in flight across compute
#pragma unroll
    for (int kkl = 0; kkl < 2; ++kkl) {
      const int kk = kt * 2 + kkl;
      if (kk + 1 < 2 * NKT) {
#pragma unroll
        for (int nf = 0; nf < NF; ++nf) wr[(kk + 1) & 1][nf] = wload(kk + 1, nf);
      }
      short8v ah[MF];
#pragma unroll
      for (int m = 0; m < MF; ++m) {
        float4 f0 = aread(kt & 1, kkl, m, 0);
        float4 f1 = aread(kt & 1, kkl, m, 1);
#pragma unroll
        for (int j = 0; j < 4; ++j) {
          ah[m][j] = bfr((&f0.x)[j]);
          ah[m][j + 4] = bfr((&f1.x)[j]);
        }
      }
#pragma unroll
      for (int nf = 0; nf < NF; ++nf)
#pragma unroll
        for (int m = 0; m < MF; ++m)
          acc[m][nf] = __builtin_amdgcn_mfma_f32_16x16x32_bf16(
              ah[m], wr[kk & 1][nf], acc[m][nf], 0, 0, 0);
    }
    __syncthreads();  // drains next-tile DMA (vmcnt0) + frees read buffer
  }

#pragma unroll
  for (int m = 0; m < MF; ++m)
#pragma unroll
    for (int nf = 0; nf < NF; ++nf) {
      const size_t r_base = R0 + wm * (M_TILE / WIM) + m * 16 + hi4 * 4;
      const int col = C0 + nf * 16 + lo16;
#pragma unroll
      for (int rr = 0; rr < 4; ++rr)
        out[(r_base + rr) * N_TOT + col] = acc[m][nf][rr];
    }
}

// ---------------- MFMA chunk scan: 16 tasks/block, 32 steps, fp16-2split F ----------------
__global__ __launch_bounds__(1024, 4) void k_mscan(const _Float16* __restrict__ Fhi,
                                                   const _Float16* __restrict__ Flo,
                                                   float* __restrict__ U,
                                                   float* __restrict__ Lst) {
  __shared__ _Float16 sh[16 * 264];
  __shared__ _Float16 sl[16 * 264];

  const int tid = threadIdx.x;
  const int wv = tid >> 6;
  const int l = tid & 63;
  const int lo16 = l & 15, hi4 = l >> 4;
  const int dcol = wv * 16 + lo16;

  const int c = blockIdx.x >> 2;
  const int b0 = (blockIdx.x & 3) * 16;

  half8v fh[8], fl[8];
#pragma unroll
  for (int kk = 0; kk < 8; ++kk) {
    const size_t fo = (size_t)dcol * 256 + kk * 32 + hi4 * 8;
    fh[kk] = *reinterpret_cast<const half8v*>(Fhi + fo);
    fl[kk] = *reinterpret_cast<const half8v*>(Flo + fo);
  }

  const size_t ustr = (size_t)TT * 256;
  float* ub = U + ((size_t)b0 * TT + c * CHUNK) * 256 + dcol;

  float u_cur[4], u_nxt[4];
#pragma unroll
  for (int r = 0; r < 4; ++r) u_cur[r] = ub[(size_t)(hi4 * 4 + r) * ustr];

  for (int k = 0; k < CHUNK; ++k) {
    if (k < CHUNK - 1) {
#pragma unroll
      for (int r = 0; r < 4; ++r)
        u_nxt[r] = ub[(size_t)(hi4 * 4 + r) * ustr + (k + 1) * 256];
    }
    float4v acc;
#pragma unroll
    for (int r = 0; r < 4; ++r) acc[r] = u_cur[r];

    if (k) {
#pragma unroll
      for (int kk = 0; kk < 8; ++kk) {
        const int ao = lo16 * 264 + kk * 32 + hi4 * 8;
        half8v ah = *reinterpret_cast<const half8v*>(&sh[ao]);
        half8v al = *reinterpret_cast<const half8v*>(&sl[ao]);
        acc = __builtin_amdgcn_mfma_f32_16x16x32_f16(ah, fh[kk], acc, 0, 0, 0);
        acc = __builtin_amdgcn_mfma_f32_16x16x32_f16(ah, fl[kk], acc, 0, 0, 0);
        acc = __builtin_amdgcn_mfma_f32_16x16x32_f16(al, fh[kk], acc, 0, 0, 0);
      }
    }

    _Float16 xh[4], xl[4];
#pragma unroll
    for (int r = 0; r < 4; ++r) {
      float x = acc[r];
      ub[(size_t)(hi4 * 4 + r) * ustr + k * 256] = x;
      if (k == CHUNK - 1) Lst[((size_t)c * BATCH + b0 + hi4 * 4 + r) * 256 + dcol] = x;
      _Float16 h = (_Float16)x;
      xh[r] = h;
      xl[r] = (_Float16)(x - (float)h);
    }
    __syncthreads();
#pragma unroll
    for (int r = 0; r < 4; ++r) {
      const int m = hi4 * 4 + r;
      sh[m * 264 + dcol] = xh[r];
      sl[m * 264 + dcol] = xl[r];
    }
    __syncthreads();
#pragma unroll
    for (int r = 0; r < 4; ++r) u_cur[r] = u_nxt[r];
  }
}

// ---------------- MFMA chunk carry: e_{c+1} = F^32 e_c + Lst[c] -> Ebf (bf16) ----------------
__global__ __launch_bounds__(1024, 4) void k_mcarry(const _Float16* __restrict__ FLhi,
                                                    const _Float16* __restrict__ FLlo,
                                                    const float* __restrict__ state0,
                                                    const float* __restrict__ Lst,
                                                    unsigned short* __restrict__ Ebf) {
  __shared__ _Float16 sh[16 * 264];
  __shared__ _Float16 sl[16 * 264];

  const int tid = threadIdx.x;
  const int wv = tid >> 6;
  const int l = tid & 63;
  const int lo16 = l & 15, hi4 = l >> 4;
  const int dcol = wv * 16 + lo16;
  const int b0 = blockIdx.x * 16;

  half8v fh[8], fl[8];
#pragma unroll
  for (int kk = 0; kk < 8; ++kk) {
    const size_t fo = (size_t)dcol * 256 + kk * 32 + hi4 * 8;
    fh[kk] = *reinterpret_cast<const half8v*>(FLhi + fo);
    fl[kk] = *reinterpret_cast<const half8v*>(FLlo + fo);
  }

#pragma unroll
  for (int r = 0; r < 4; ++r) {
    const int m = hi4 * 4 + r;
    float x = state0[(size_t)(b0 + m) * 256 + dcol];
    Ebf[(size_t)(b0 + m) * 256 + dcol] = f2bf(x);
    _Float16 h = (_Float16)x;
    sh[m * 264 + dcol] = h;
    sl[m * 264 + dcol] = (_Float16)(x - (float)h);
  }
  __syncthreads();

  for (int cstep = 0; cstep < NCHUNK - 1; ++cstep) {
    float4v acc;
#pragma unroll
    for (int r = 0; r < 4; ++r)
      acc[r] = Lst[((size_t)cstep * BATCH + b0 + hi4 * 4 + r) * 256 + dcol];
#pragma unroll
    for (int kk = 0; kk < 8; ++kk) {
      const int ao = lo16 * 264 + kk * 32 + hi4 * 8;
      half8v ah = *reinterpret_cast<const half8v*>(&sh[ao]);
      half8v al = *reinterpret_cast<const half8v*>(&sl[ao]);
      acc = __builtin_amdgcn_mfma_f32_16x16x32_f16(ah, fh[kk], acc, 0, 0, 0);
      acc = __builtin_amdgcn_mfma_f32_16x16x32_f16(ah, fl[kk], acc, 0, 0, 0);
      acc = __builtin_amdgcn_mfma_f32_16x16x32_f16(al, fh[kk], acc, 0, 0, 0);
    }
    _Float16 xh[4], xl[4];
#pragma unroll
    for (int r = 0; r < 4; ++r) {
      float x = acc[r];
      Ebf[((size_t)(cstep + 1) * BATCH + b0 + hi4 * 4 + r) * 256 + dcol] = f2bf(x);
      _Float16 h = (_Float16)x;
      xh[r] = h;
      xl[r] = (_Float16)(x - (float)h);
    }
    __syncthreads();
#pragma unroll
    for (int r = 0; r < 4; ++r) {
      const int m = hi4 * 4 + r;
      sh[m * 264 + dcol] = xh[r];
      sl[m * 264 + dcol] = xl[r];
    }
    __syncthreads();
  }
}

// ---------------- correction: states[task, j, :] += F^{j+1} @ e[task]  (bf16 MFMA) ----------------
// T14 issue-early/use-late: the states RMW read is prefetched into registers at
// kernel start (32 independent coalesced loads), the 64-MFMA body hides the HBM
// latency, then add+store is fire-and-forget. launch_bounds(256,4) caps VGPR at
// 128 (~100 needed) so the compiler has no pressure incentive to sink the loads.
__global__ __launch_bounds__(256, 4) void k_corr(const unsigned short* __restrict__ Ebf,
                                                 const unsigned short* __restrict__ stackbf,
                                                 float* __restrict__ states) {
  const int tb = blockIdx.x & 127;
  const int jb = blockIdx.x >> 7;
  const int tid = threadIdx.x;
  const int w = tid >> 6;
  const int l = tid & 63;
  const int lo = l & 15, hi = l >> 4;

  const int M0 = tb * 32 + (w & 1) * 16;
  const int nbase = (w >> 1) * 128;
  const unsigned short* Bj = stackbf + (size_t)jb * 65536;

  // prefetch the y values this wave will update (independent of all compute)
  float ypre[8][4];
#pragma unroll
  for (int nf = 0; nf < 8; ++nf) {
    const int d = nbase + nf * 16 + lo;
#pragma unroll
    for (int r = 0; r < 4; ++r) {
      const int task = M0 + hi * 4 + r;
      const int bb = task & 63, cc = task >> 6;
      ypre[nf][r] = states[(((size_t)bb * TT) + cc * CHUNK + jb) * 256 + d];
    }
  }

  float4v acc[8];
#pragma unroll
  for (int nf = 0; nf < 8; ++nf) acc[nf] = (float4v){0.f, 0.f, 0.f, 0.f};

#pragma unroll
  for (int kk = 0; kk < 8; ++kk) {
    const int k0 = kk * 32;
    short8v a = *reinterpret_cast<const short8v*>(Ebf + (size_t)(M0 + lo) * 256 + k0 + hi * 8);
#pragma unroll
    for (int nf = 0; nf < 8; ++nf) {
      const int d0 = nbase + nf * 16;
      short8v bv = *reinterpret_cast<const short8v*>(Bj + (size_t)(d0 + lo) * 256 + k0 + hi * 8);
      acc[nf] = __builtin_amdgcn_mfma_f32_16x16x32_bf16(a, bv, acc[nf], 0, 0, 0);
    }
  }

#pragma unroll
  for (int nf = 0; nf < 8; ++nf) {
    const int d = nbase + nf * 16 + lo;
#pragma unroll
    for (int r = 0; r < 4; ++r) {
      const int task = M0 + hi * 4 + r;
      const int bb = task & 63, cc = task >> 6;
      states[(((size_t)bb * TT) + cc * CHUNK + jb) * 256 + d] = ypre[nf][r] + acc[nf][r];
    }
  }
}

extern "C" void kernel_launch(void* const* d_in, const int* in_sizes, int n_in,
                              void* d_out, int out_size, void* d_ws, size_t ws_size,
                              hipStream_t stream) {
  const float* state  = (const float*)d_in[0];
  const float* inputs = (const float*)d_in[1];
  const float* eps_W  = (const float*)d_in[2];
  const float* eps_V  = (const float*)d_in[3];
  const float* F      = (const float*)d_in[4];
  const float* B_mat  = (const float*)d_in[5];
  const float* H      = (const float*)d_in[6];
  const float* SW     = (const float*)d_in[7];
  const float* SV     = (const float*)d_in[8];

  float* out = (float*)d_out;
  float* states_out = out;                                 // [64][2048][256]
  float* obs_out = out + (size_t)BATCH * TT * S_DIM;       // [64][2048][64]

  // ws (~720 KB): bf16 weights + fp16 F splits
  unsigned short* ws16 = (unsigned short*)d_ws;
  unsigned short* whi1 = ws16;                 // [256][320]
  unsigned short* whi2 = whi1 + 81920;         // [64][320]
  _Float16* Fhi  = (_Float16*)(whi2 + 20480);  // [256][256]
  _Float16* Flo  = Fhi + 65536;
  _Float16* FLhi = Flo + 65536;                // (F^32) [256][256]
  _Float16* FLlo = FLhi + 65536;

  // big scratch in the dead obs region (18 MB of 33.5 MB)
  float* Lst              = obs_out;                                   // [64][64][256] f32
  float* stack_F          = Lst + (size_t)NCHUNK * BATCH * 256;        // [32][256][256] f32
  unsigned short* stackbf = (unsigned short*)(stack_F + (size_t)32 * 65536);
  unsigned short* Ebf     = stackbf + (size_t)32 * 65536;              // [64][64][256] bf16

  // power stack F^1..F^32 by doubling
  hipMemcpyAsync(stack_F, F, 65536 * sizeof(float), hipMemcpyDeviceToDevice, stream);
  k_powstage<<<1 * 256, 256, 0, stream>>>(stack_F, 1);
  k_powstage<<<2 * 256, 256, 0, stream>>>(stack_F, 2);
  k_powstage<<<4 * 256, 256, 0, stream>>>(stack_F, 4);
  k_powstage<<<8 * 256, 256, 0, stream>>>(stack_F, 8);
  k_powstage<<<16 * 256, 256, 0, stream>>>(stack_F, 16);
  k_bfcvt<<<32 * 65536 / 4 / 256, 256, 0, stream>>>(stack_F, stackbf);

  // fp16 splits for the scan/carry matrices
  k_fsplit16<<<256, 256, 0, stream>>>(F, Fhi, Flo);
  k_fsplit16<<<256, 256, 0, stream>>>(stack_F + (size_t)31 * 65536, FLhi, FLlo);

  // bf16 weights (K-major concat rows)
  k_wcvt<<<320, 256, 0, stream>>>(B_mat, SW, 64, 256, whi1, 256 * 320);
  k_wcvt<<<80, 256, 0, stream>>>(H, SV, 256, 64, whi2, 64 * 320);

  // U = inputs@B^T + eps_W@SW^T  (2-phase LDS pipeline, global_load_lds)
  k_tgemm<256, 64, 256, 64, 1, 4><<<BATCH * TT / 64, 256, 0, stream>>>(
      inputs, eps_W, whi1, states_out);

  // pass 1: MFMA local scans (zero init), y in place + Lst
  k_mscan<<<NTASK / 16, 1024, 0, stream>>>(Fhi, Flo, states_out, Lst);

  // carry across chunks -> Ebf
  k_mcarry<<<BATCH / 16, 1024, 0, stream>>>(FLhi, FLlo, state, Lst, Ebf);

  // correction: states = y + F^{j+1} e  (prefetched RMW)
  k_corr<<<32 * 128, 256, 0, stream>>>(Ebf, stackbf, states_out);

  // observations = states@H^T + eps_V@SV^T
  k_tgemm<64, 256, 64, 128, 4, 1><<<BATCH * TT / 128, 256, 0, stream>>>(
      states_out, eps_V, whi2, obs_out);
}

// Round 13
// 425.028 us; speedup vs baseline: 1.3428x; 1.3428x over previous
//
#include <hip/hip_runtime.h>
#include <hip/hip_bf16.h>

#define S_DIM 256
#define I_DIM 64
#define O_DIM 64
#define BATCH 64
#define TT 2048
#define CHUNK 32
#define NCHUNK (TT / CHUNK)     // 64
#define NTASK (BATCH * TT / CHUNK)  // 4096

typedef __attribute__((ext_vector_type(8))) short short8v;      // 8 bf16
typedef _Float16 half8v __attribute__((ext_vector_type(8)));    // 8 fp16
typedef __attribute__((ext_vector_type(4))) float float4v;      // MFMA acc

__device__ inline unsigned short f2bf(float f) {
  unsigned x = __float_as_uint(f);
  unsigned r = (x + 0x7FFFu + ((x >> 16) & 1u)) >> 16;  // RNE
  return (unsigned short)r;
}
__device__ inline short bfr(float x) {
  __hip_bfloat16 h = __float2bfloat16(x);
  return __builtin_bit_cast(short, h);
}

// global -> LDS direct DMA, 16B per lane (dst = wave-uniform base + lane*16)
__device__ inline void gload16(const float* g, float* lds) {
  __builtin_amdgcn_global_load_lds(
      (const __attribute__((address_space(1))) unsigned int*)g,
      (__attribute__((address_space(3))) unsigned int*)lds, 16, 0, 0);
}

// ------------- matsq: dst = src @ src (256x256 f32, L2-resident) -------------
__global__ void k_matsq(const float* __restrict__ src, float* __restrict__ dst) {
  const int i = blockIdx.x;
  const int j = threadIdx.x;
  float acc = 0.f;
#pragma unroll 8
  for (int k = 0; k < 256; ++k) acc += src[i * 256 + k] * src[k * 256 + j];
  dst[i * 256 + j] = acc;
}

// ------------- f32 matrix -> fp16 hi/lo split -------------
__global__ void k_fsplit16(const float* __restrict__ src, _Float16* __restrict__ hi,
                           _Float16* __restrict__ lo) {
  int idx = blockIdx.x * 256 + threadIdx.x;
  float a = src[idx];
  _Float16 h = (_Float16)a;
  hi[idx] = h;
  lo[idx] = (_Float16)(a - (float)h);
}

// ------------- weight convert: Wd[n][k] = concat(s1,s2) rows, single bf16 -------------
__global__ void k_wcvt(const float* __restrict__ s1, const float* __restrict__ s2,
                       int K1, int K2, unsigned short* __restrict__ hi, int total) {
  int idx = blockIdx.x * 256 + threadIdx.x;
  if (idx >= total) return;
  int KT = K1 + K2;
  int n = idx / KT, k = idx - n * KT;
  float a = (k < K1) ? s1[n * K1 + k] : s2[n * K2 + (k - K1)];
  hi[idx] = f2bf(a);
}

// ---------------- 2-phase LDS-pipelined bf16 MFMA GEMM: out = [A1|A2] @ W^T ----------------
template <int N_TOT, int K1, int K2, int M_TILE, int WIM, int WIN>
__global__ __launch_bounds__(256, 3) void k_tgemm(
    const float* __restrict__ A1, const float* __restrict__ A2,
    const unsigned short* __restrict__ W, float* __restrict__ out) {
  constexpr int KT = K1 + K2;   // 320
  constexpr int NKT = KT / 64;  // 5 K-tiles
  constexpr int MF = M_TILE / WIM / 16;
  constexpr int NF = N_TOT / WIN / 16;
  constexpr int LOGM = (M_TILE == 64) ? 6 : 7;
  constexpr int CPW = M_TILE / 16;  // gload calls per wave per K-tile

  __shared__ float als[2][M_TILE * 64];

  const int tid = threadIdx.x;
  const int wv = tid >> 6, lane = tid & 63;
  const int lo16 = lane & 15, hi4 = lane >> 4;
  const int wm = wv % WIM, wn = wv / WIM;
  const size_t R0 = (size_t)blockIdx.x * M_TILE;
  const int C0 = wn * (N_TOT / WIN);

  auto stage = [&](int buf, int kt) {
#pragma unroll
    for (int c = 0; c < CPW; ++c) {
      const int i = wv * CPW + c;
      const int s = i * 64 + lane;
      const int row = s & (M_TILE - 1);
      const int g = s >> LOGM;
      const int k0 = kt * 64;
      const float* src = (k0 < K1) ? A1 + (R0 + row) * K1 + k0 + g * 4
                                   : A2 + (R0 + row) * K2 + (k0 - K1) + g * 4;
      gload16(src, &als[buf][i * 256]);
    }
  };
  auto aread = [&](int buf, int kkl, int m, int h) -> float4 {
    const int row = wm * (M_TILE / WIM) + m * 16 + lo16;
    const int g = kkl * 8 + hi4 * 2 + h;
    return *reinterpret_cast<const float4*>(&als[buf][(g * M_TILE + row) * 4]);
  };
  auto wload = [&](int kk, int nf) -> short8v {
    return *reinterpret_cast<const short8v*>(
        W + (size_t)(C0 + nf * 16 + lo16) * KT + kk * 32 + hi4 * 8);
  };

  float4v acc[MF][NF];
#pragma unroll
  for (int m = 0; m < MF; ++m)
#pragma unroll
    for (int n = 0; n < NF; ++n) acc[m][n] = (float4v){0.f, 0.f, 0.f, 0.f};

  short8v wr[2][NF];
  stage(0, 0);
#pragma unroll
  for (int nf = 0; nf < NF; ++nf) wr[0][nf] = wload(0, nf);
  __syncthreads();

#pragma unroll
  for (int kt = 0; kt < NKT; ++kt) {
    if (kt + 1 < NKT) stage((kt + 1) & 1, kt + 1);  // DMA in flight across compute
#pragma unroll
    for (int kkl = 0; kkl < 2; ++kkl) {
      const int kk = kt * 2 + kkl;
      if (kk + 1 < 2 * NKT) {
#pragma unroll
        for (int nf = 0; nf < NF; ++nf) wr[(kk + 1) & 1][nf] = wload(kk + 1, nf);
      }
      short8v ah[MF];
#pragma unroll
      for (int m = 0; m < MF; ++m) {
        float4 f0 = aread(kt & 1, kkl, m, 0);
        float4 f1 = aread(kt & 1, kkl, m, 1);
#pragma unroll
        for (int j = 0; j < 4; ++j) {
          ah[m][j] = bfr((&f0.x)[j]);
          ah[m][j + 4] = bfr((&f1.x)[j]);
        }
      }
#pragma unroll
      for (int nf = 0; nf < NF; ++nf)
#pragma unroll
        for (int m = 0; m < MF; ++m)
          acc[m][nf] = __builtin_amdgcn_mfma_f32_16x16x32_bf16(
              ah[m], wr[kk & 1][nf], acc[m][nf], 0, 0, 0);
    }
    __syncthreads();  // drains next-tile DMA (vmcnt0) + frees read buffer
  }

#pragma unroll
  for (int m = 0; m < MF; ++m)
#pragma unroll
    for (int nf = 0; nf < NF; ++nf) {
      const size_t r_base = R0 + wm * (M_TILE / WIM) + m * 16 + hi4 * 4;
      const int col = C0 + nf * 16 + lo16;
#pragma unroll
      for (int rr = 0; rr < 4; ++rr)
        out[(r_base + rr) * N_TOT + col] = acc[m][nf][rr];
    }
}

// ---------------- MFMA chunk scan, two passes ----------------
// MODE 0: zero-init local scan; READ-ONLY over U; emits Lst[c][b][:] (last state).
// MODE 1: true scan, init from E[c][b][:] (f32); writes states over U in place.
// 3 independent MFMA accumulator chains (hh/hl/lh) cut the serial dep chain 3x.
template <int MODE>
__global__ __launch_bounds__(1024, 4) void k_mscan(const _Float16* __restrict__ Fhi,
                                                   const _Float16* __restrict__ Flo,
                                                   float* __restrict__ U,
                                                   const float* __restrict__ E,
                                                   float* __restrict__ Lst) {
  __shared__ _Float16 sh[16 * 264];
  __shared__ _Float16 sl[16 * 264];

  const int tid = threadIdx.x;
  const int wv = tid >> 6;
  const int l = tid & 63;
  const int lo16 = l & 15, hi4 = l >> 4;
  const int dcol = wv * 16 + lo16;

  const int c = blockIdx.x >> 2;
  const int b0 = (blockIdx.x & 3) * 16;

  half8v fh[8], fl[8];
#pragma unroll
  for (int kk = 0; kk < 8; ++kk) {
    const size_t fo = (size_t)dcol * 256 + kk * 32 + hi4 * 8;
    fh[kk] = *reinterpret_cast<const half8v*>(Fhi + fo);
    fl[kk] = *reinterpret_cast<const half8v*>(Flo + fo);
  }

  if (MODE == 1) {  // seed state from E (f32)
#pragma unroll
    for (int r = 0; r < 4; ++r) {
      const int m = hi4 * 4 + r;
      float x = E[((size_t)c * BATCH + b0 + m) * 256 + dcol];
      _Float16 h = (_Float16)x;
      sh[m * 264 + dcol] = h;
      sl[m * 264 + dcol] = (_Float16)(x - (float)h);
    }
    __syncthreads();
  }

  const size_t ustr = (size_t)TT * 256;
  float* ub = U + ((size_t)b0 * TT + c * CHUNK) * 256 + dcol;

  float u_cur[4], u_nxt[4];
#pragma unroll
  for (int r = 0; r < 4; ++r) u_cur[r] = ub[(size_t)(hi4 * 4 + r) * ustr];

  for (int k = 0; k < CHUNK; ++k) {
    if (k < CHUNK - 1) {
#pragma unroll
      for (int r = 0; r < 4; ++r)
        u_nxt[r] = ub[(size_t)(hi4 * 4 + r) * ustr + (k + 1) * 256];
    }
    float4v a0, a1, a2;
#pragma unroll
    for (int r = 0; r < 4; ++r) {
      a0[r] = u_cur[r];
      a1[r] = 0.f;
      a2[r] = 0.f;
    }

    if (MODE == 1 || k) {
#pragma unroll
      for (int kk = 0; kk < 8; ++kk) {
        const int ao = lo16 * 264 + kk * 32 + hi4 * 8;
        half8v ah = *reinterpret_cast<const half8v*>(&sh[ao]);
        half8v al = *reinterpret_cast<const half8v*>(&sl[ao]);
        a0 = __builtin_amdgcn_mfma_f32_16x16x32_f16(ah, fh[kk], a0, 0, 0, 0);
        a1 = __builtin_amdgcn_mfma_f32_16x16x32_f16(ah, fl[kk], a1, 0, 0, 0);
        a2 = __builtin_amdgcn_mfma_f32_16x16x32_f16(al, fh[kk], a2, 0, 0, 0);
      }
    }

    _Float16 xh[4], xl[4];
#pragma unroll
    for (int r = 0; r < 4; ++r) {
      float x = a0[r] + a1[r] + a2[r];
      if (MODE == 1) ub[(size_t)(hi4 * 4 + r) * ustr + k * 256] = x;
      if (MODE == 0 && k == CHUNK - 1)
        Lst[((size_t)c * BATCH + b0 + hi4 * 4 + r) * 256 + dcol] = x;
      _Float16 h = (_Float16)x;
      xh[r] = h;
      xl[r] = (_Float16)(x - (float)h);
    }
    __syncthreads();  // all waves done reading sh/sl for step k
#pragma unroll
    for (int r = 0; r < 4; ++r) {
      const int m = hi4 * 4 + r;
      sh[m * 264 + dcol] = xh[r];
      sl[m * 264 + dcol] = xl[r];
    }
    __syncthreads();  // writes visible for step k+1
#pragma unroll
    for (int r = 0; r < 4; ++r) u_cur[r] = u_nxt[r];
  }
}

// ---------------- chunk carry: e_{c+1} = F^32 e_c + Lst[c] -> E (f32) ----------------
__global__ __launch_bounds__(1024, 4) void k_mcarry(const _Float16* __restrict__ FLhi,
                                                    const _Float16* __restrict__ FLlo,
                                                    const float* __restrict__ state0,
                                                    const float* __restrict__ Lst,
                                                    float* __restrict__ E) {
  __shared__ _Float16 sh[16 * 264];
  __shared__ _Float16 sl[16 * 264];

  const int tid = threadIdx.x;
  const int wv = tid >> 6;
  const int l = tid & 63;
  const int lo16 = l & 15, hi4 = l >> 4;
  const int dcol = wv * 16 + lo16;
  const int b0 = blockIdx.x * 16;

  half8v fh[8], fl[8];
#pragma unroll
  for (int kk = 0; kk < 8; ++kk) {
    const size_t fo = (size_t)dcol * 256 + kk * 32 + hi4 * 8;
    fh[kk] = *reinterpret_cast<const half8v*>(FLhi + fo);
    fl[kk] = *reinterpret_cast<const half8v*>(FLlo + fo);
  }

#pragma unroll
  for (int r = 0; r < 4; ++r) {
    const int m = hi4 * 4 + r;
    float x = state0[(size_t)(b0 + m) * 256 + dcol];
    E[(size_t)(b0 + m) * 256 + dcol] = x;  // E[0] = initial state
    _Float16 h = (_Float16)x;
    sh[m * 264 + dcol] = h;
    sl[m * 264 + dcol] = (_Float16)(x - (float)h);
  }
  __syncthreads();

  for (int cstep = 0; cstep < NCHUNK - 1; ++cstep) {
    float4v a0, a1, a2;
#pragma unroll
    for (int r = 0; r < 4; ++r) {
      a0[r] = Lst[((size_t)cstep * BATCH + b0 + hi4 * 4 + r) * 256 + dcol];
      a1[r] = 0.f;
      a2[r] = 0.f;
    }
#pragma unroll
    for (int kk = 0; kk < 8; ++kk) {
      const int ao = lo16 * 264 + kk * 32 + hi4 * 8;
      half8v ah = *reinterpret_cast<const half8v*>(&sh[ao]);
      half8v al = *reinterpret_cast<const half8v*>(&sl[ao]);
      a0 = __builtin_amdgcn_mfma_f32_16x16x32_f16(ah, fh[kk], a0, 0, 0, 0);
      a1 = __builtin_amdgcn_mfma_f32_16x16x32_f16(ah, fl[kk], a1, 0, 0, 0);
      a2 = __builtin_amdgcn_mfma_f32_16x16x32_f16(al, fh[kk], a2, 0, 0, 0);
    }
    _Float16 xh[4], xl[4];
#pragma unroll
    for (int r = 0; r < 4; ++r) {
      float x = a0[r] + a1[r] + a2[r];
      E[((size_t)(cstep + 1) * BATCH + b0 + hi4 * 4 + r) * 256 + dcol] = x;
      _Float16 h = (_Float16)x;
      xh[r] = h;
      xl[r] = (_Float16)(x - (float)h);
    }
    __syncthreads();
#pragma unroll
    for (int r = 0; r < 4; ++r) {
      const int m = hi4 * 4 + r;
      sh[m * 264 + dcol] = xh[r];
      sl[m * 264 + dcol] = xl[r];
    }
    __syncthreads();
  }
}

extern "C" void kernel_launch(void* const* d_in, const int* in_sizes, int n_in,
                              void* d_out, int out_size, void* d_ws, size_t ws_size,
                              hipStream_t stream) {
  const float* state  = (const float*)d_in[0];
  const float* inputs = (const float*)d_in[1];
  const float* eps_W  = (const float*)d_in[2];
  const float* eps_V  = (const float*)d_in[3];
  const float* F      = (const float*)d_in[4];
  const float* B_mat  = (const float*)d_in[5];
  const float* H      = (const float*)d_in[6];
  const float* SW     = (const float*)d_in[7];
  const float* SV     = (const float*)d_in[8];

  float* out = (float*)d_out;
  float* states_out = out;                                 // [64][2048][256]
  float* obs_out = out + (size_t)BATCH * TT * S_DIM;       // [64][2048][64]

  // ws (~730 KB): bf16 weights + fp16 F splits
  unsigned short* ws16 = (unsigned short*)d_ws;
  unsigned short* whi1 = ws16;                 // [256][320]
  unsigned short* whi2 = whi1 + 81920;         // [64][320]
  _Float16* Fhi  = (_Float16*)(whi2 + 20480);  // [256][256]
  _Float16* Flo  = Fhi + 65536;
  _Float16* FLhi = Flo + 65536;                // (F^32) [256][256]
  _Float16* FLlo = FLhi + 65536;

  // big scratch in the dead obs region (8.7 MB of 33.5 MB)
  float* Lst = obs_out;                                    // [64][64][256] f32 (4 MB)
  float* E   = Lst + (size_t)NCHUNK * BATCH * 256;         // [64][64][256] f32 (4 MB)
  float* Pa  = E + (size_t)NCHUNK * BATCH * 256;           // [256][256] ping
  float* Pb  = Pa + 65536;                                 // [256][256] pong

  // F^32 via 5 squarings (only power needed now)
  k_matsq<<<256, 256, 0, stream>>>(F, Pa);    // F^2
  k_matsq<<<256, 256, 0, stream>>>(Pa, Pb);   // F^4
  k_matsq<<<256, 256, 0, stream>>>(Pb, Pa);   // F^8
  k_matsq<<<256, 256, 0, stream>>>(Pa, Pb);   // F^16
  k_matsq<<<256, 256, 0, stream>>>(Pb, Pa);   // F^32

  // fp16 splits for scan/carry matrices
  k_fsplit16<<<256, 256, 0, stream>>>(F, Fhi, Flo);
  k_fsplit16<<<256, 256, 0, stream>>>(Pa, FLhi, FLlo);

  // bf16 weights (K-major concat rows)
  k_wcvt<<<320, 256, 0, stream>>>(B_mat, SW, 64, 256, whi1, 256 * 320);
  k_wcvt<<<80, 256, 0, stream>>>(H, SV, 256, 64, whi2, 64 * 320);

  // U = inputs@B^T + eps_W@SW^T  (2-phase LDS pipeline, global_load_lds)
  k_tgemm<256, 64, 256, 64, 1, 4><<<BATCH * TT / 64, 256, 0, stream>>>(
      inputs, eps_W, whi1, states_out);

  // pass 1: local scans (zero init), READ-ONLY, emit Lst
  k_mscan<0><<<NTASK / 16, 1024, 0, stream>>>(Fhi, Flo, states_out, E, Lst);

  // carry across chunks -> E (f32)
  k_mcarry<<<BATCH / 16, 1024, 0, stream>>>(FLhi, FLlo, state, Lst, E);

  // pass 2: true scans seeded from E, write states in place
  k_mscan<1><<<NTASK / 16, 1024, 0, stream>>>(Fhi, Flo, states_out, E, Lst);

  // observations = states@H^T + eps_V@SV^T
  k_tgemm<64, 256, 64, 128, 4, 1><<<BATCH * TT / 128, 256, 0, stream>>>(
      states_out, eps_V, whi2, obs_out);
}